// Round 11
// baseline (57.719 us; speedup 1.0000x reference)
//
#include <hip/hip_runtime.h>
#include <cstdint>
#include <cstddef>

constexpr int D = 64;
constexpr int TWO_D = 128;

typedef __attribute__((ext_vector_type(8))) short bf16x8;
typedef __attribute__((ext_vector_type(4))) float f32x4;
typedef __attribute__((ext_vector_type(4))) unsigned short u16x4;

static __device__ __forceinline__ short f2bf(float x) {
    unsigned u = __builtin_bit_cast(unsigned, x);
    u += 0x7fffu + ((u >> 16) & 1u);          // round-to-nearest-even
    return (short)(u >> 16);
}
static __device__ __forceinline__ float bf2f(short h) {
    return __builtin_bit_cast(float, ((unsigned)(unsigned short)h) << 16);
}

// ---------------------------------------------------------------------------
// Kernel 1: projection tables, tiled fp32 GEMM + W2-fragment pack block.
//   blocks [0, nPB):        P16[r,:] = bf16( v_to_e[r,:] . att1_w[:,0:D]^T )
//   blocks [nPB, nPB+nSB):  S[b,:]   = u_to_e[nodes[b],:] . att1_w[:,D:2D]^T + b1
//   block  nPB+nSB:         W2F = bf16 MFMA A-fragments of W2
// ---------------------------------------------------------------------------
__global__ __launch_bounds__(256) void proj_gemm(
    const float* __restrict__ v_to_e, const float* __restrict__ u_to_e,
    const int* __restrict__ nodes,
    const float* __restrict__ att1_w, const float* __restrict__ att1_b,
    const float* __restrict__ att2_w,
    unsigned short* __restrict__ P16, float* __restrict__ S,
    unsigned short* __restrict__ W2F,
    int NV, int Bn, int nPB)
{
    const int tid = threadIdx.x;

    if ((int)blockIdx.x == nPB + (Bn + 63) / 64) {   // W2 pack block
        if (tid < 64) {
            const int plg = tid >> 4, plc = tid & 15;
#pragma unroll
            for (int tc = 0; tc < 4; ++tc)
#pragma unroll
                for (int ks = 0; ks < 2; ++ks) {
                    const float* src =
                        att2_w + (tc * 16 + plc) * D + ks * 32 + plg * 8;
                    const float4 a = *(const float4*)src;
                    const float4 c = *(const float4*)(src + 4);
                    bf16x8 f;
                    f[0] = f2bf(a.x); f[1] = f2bf(a.y);
                    f[2] = f2bf(a.z); f[3] = f2bf(a.w);
                    f[4] = f2bf(c.x); f[5] = f2bf(c.y);
                    f[6] = f2bf(c.z); f[7] = f2bf(c.w);
                    *(bf16x8*)(W2F + ((size_t)(tc * 2 + ks) * 64 + tid) * 8) = f;
                }
        }
        return;
    }

    constexpr int ST = 68;
    __shared__ float xs[64 * ST];
    __shared__ float ws[64 * ST];

    const bool isS = ((int)blockIdx.x >= nPB);
    const int base = (isS ? ((int)blockIdx.x - nPB) : (int)blockIdx.x) * 64;
    const int nRows = isS ? Bn : NV;
    const int woff  = isS ? D : 0;
    const float* X  = isS ? u_to_e : v_to_e;

#pragma unroll
    for (int it = 0; it < 4; ++it) {
        const int flat = it * 256 + tid;
        const int dd = flat >> 4, f4 = flat & 15;
        const float4 w = *(const float4*)(att1_w + dd * TWO_D + woff + f4 * 4);
        ws[(f4 * 4 + 0) * ST + dd] = w.x;
        ws[(f4 * 4 + 1) * ST + dd] = w.y;
        ws[(f4 * 4 + 2) * ST + dd] = w.z;
        ws[(f4 * 4 + 3) * ST + dd] = w.w;
    }
#pragma unroll
    for (int it = 0; it < 4; ++it) {
        const int flat = it * 256 + tid;
        const int r = flat >> 4, f4 = flat & 15;
        int gr = base + r;
        if (gr >= nRows) gr = nRows - 1;
        const int row = isS ? nodes[gr] : gr;
        const float4 x = *(const float4*)(X + (size_t)row * D + f4 * 4);
        xs[(f4 * 4 + 0) * ST + r] = x.x;
        xs[(f4 * 4 + 1) * ST + r] = x.y;
        xs[(f4 * 4 + 2) * ST + r] = x.z;
        xs[(f4 * 4 + 3) * ST + r] = x.w;
    }
    __syncthreads();

    const int d0 = (tid & 15) * 4;
    const int r0 = (tid >> 4) * 4;
    float acc[4][4];
#pragma unroll
    for (int i = 0; i < 4; ++i)
#pragma unroll
        for (int j = 0; j < 4; ++j) acc[i][j] = 0.f;

#pragma unroll 8
    for (int f = 0; f < D; ++f) {
        const float4 w = *(const float4*)&ws[f * ST + d0];
        const float4 x = *(const float4*)&xs[f * ST + r0];
        const float wv[4] = {w.x, w.y, w.z, w.w};
        const float xv[4] = {x.x, x.y, x.z, x.w};
#pragma unroll
        for (int ri = 0; ri < 4; ++ri)
#pragma unroll
            for (int di = 0; di < 4; ++di)
                acc[ri][di] += xv[ri] * wv[di];
    }

    if (isS) {
        float bv[4];
#pragma unroll
        for (int di = 0; di < 4; ++di) bv[di] = att1_b[d0 + di];
#pragma unroll
        for (int ri = 0; ri < 4; ++ri) {
            const int gr = base + r0 + ri;
            if (gr < nRows) {
                float4 o = {acc[ri][0] + bv[0], acc[ri][1] + bv[1],
                            acc[ri][2] + bv[2], acc[ri][3] + bv[3]};
                *(float4*)(S + (size_t)gr * D + d0) = o;
            }
        }
    } else {
#pragma unroll
        for (int ri = 0; ri < 4; ++ri) {
            const int gr = base + r0 + ri;
            if (gr < nRows) {
                u16x4 o;
                o[0] = (unsigned short)f2bf(acc[ri][0]);
                o[1] = (unsigned short)f2bf(acc[ri][1]);
                o[2] = (unsigned short)f2bf(acc[ri][2]);
                o[3] = (unsigned short)f2bf(acc[ri][3]);
                *(u16x4*)(P16 + (size_t)gr * D + d0) = o;
            }
        }
    }
}

// ---------------------------------------------------------------------------
// Kernel 2 (score only, slim): block = one b, wave wslot = k-tile.
// Transposed MFMA with per-tc fused epilogue (one live f32x4 acc).
// Writes NORMALIZED attention weights ATT[b][0..63] (0 for k >= deg).
// ---------------------------------------------------------------------------
__global__ __launch_bounds__(256, 8) void score_mfma(
    const int* __restrict__ history, const int* __restrict__ degrees,
    const float* __restrict__ att2_b, const float* __restrict__ att3_w,
    const unsigned short* __restrict__ P16, const float* __restrict__ S,
    const unsigned short* __restrict__ W2F,
    float* __restrict__ ATT, int Bn, int K)
{
    __shared__ float mxs[4];
    __shared__ float sms[4];

    const int b     = (int)blockIdx.x;
    const int wslot = threadIdx.x >> 6;
    const int l     = threadIdx.x & 63;
    const int lg    = l >> 4;
    const int lc    = l & 15;
    const int deg   = degrees[b];                 // uniform
    const bool live = (wslot * 16 < deg);         // wave-uniform
    const bool act  = (wslot * 16 + lc < deg);

    float m_w = -1e30f, ex = 0.f;
    if (live) {
        int kk = wslot * 16 + lc;
        if (kk > K - 1) kk = K - 1;
        const int vrow = history[(size_t)b * K + kk];

        // ---- h1 fragment: P16 gather + S row ----
        const bf16x8 praw0 = *(const bf16x8*)(P16 + (size_t)vrow * D + lg * 8);
        const bf16x8 praw1 = *(const bf16x8*)(P16 + (size_t)vrow * D + 32 + lg * 8);
        const float* sp = S + (size_t)b * D;
        const float4 s00 = *(const float4*)(sp + lg * 8);
        const float4 s01 = *(const float4*)(sp + lg * 8 + 4);
        const float4 s10 = *(const float4*)(sp + 32 + lg * 8);
        const float4 s11 = *(const float4*)(sp + 32 + lg * 8 + 4);

        bf16x8 af0, af1;
        af0[0] = f2bf(fmaxf(bf2f(praw0[0]) + s00.x, 0.f));
        af0[1] = f2bf(fmaxf(bf2f(praw0[1]) + s00.y, 0.f));
        af0[2] = f2bf(fmaxf(bf2f(praw0[2]) + s00.z, 0.f));
        af0[3] = f2bf(fmaxf(bf2f(praw0[3]) + s00.w, 0.f));
        af0[4] = f2bf(fmaxf(bf2f(praw0[4]) + s01.x, 0.f));
        af0[5] = f2bf(fmaxf(bf2f(praw0[5]) + s01.y, 0.f));
        af0[6] = f2bf(fmaxf(bf2f(praw0[6]) + s01.z, 0.f));
        af0[7] = f2bf(fmaxf(bf2f(praw0[7]) + s01.w, 0.f));
        af1[0] = f2bf(fmaxf(bf2f(praw1[0]) + s10.x, 0.f));
        af1[1] = f2bf(fmaxf(bf2f(praw1[1]) + s10.y, 0.f));
        af1[2] = f2bf(fmaxf(bf2f(praw1[2]) + s10.z, 0.f));
        af1[3] = f2bf(fmaxf(bf2f(praw1[3]) + s10.w, 0.f));
        af1[4] = f2bf(fmaxf(bf2f(praw1[4]) + s11.x, 0.f));
        af1[5] = f2bf(fmaxf(bf2f(praw1[5]) + s11.y, 0.f));
        af1[6] = f2bf(fmaxf(bf2f(praw1[6]) + s11.z, 0.f));
        af1[7] = f2bf(fmaxf(bf2f(praw1[7]) + s11.w, 0.f));

        // ---- per-tc MFMA + fused epilogue (one live acc) ----
        float part = 0.f;
#pragma unroll
        for (int tc = 0; tc < 4; ++tc) {
            f32x4 acc = (f32x4)0.f;
            const bf16x8 w0 = *(const bf16x8*)(
                W2F + ((size_t)(tc * 2 + 0) * 64 + l) * 8);
            acc = __builtin_amdgcn_mfma_f32_16x16x32_bf16(w0, af0, acc, 0, 0, 0);
            const bf16x8 w1 = *(const bf16x8*)(
                W2F + ((size_t)(tc * 2 + 1) * 64 + l) * 8);
            acc = __builtin_amdgcn_mfma_f32_16x16x32_bf16(w1, af1, acc, 0, 0, 0);
            const float4 b2v = *(const float4*)(att2_b + tc * 16 + lg * 4);
            const float4 w3v = *(const float4*)(att3_w + tc * 16 + lg * 4);
            part += fmaxf(acc[0] + b2v.x, 0.f) * w3v.x;
            part += fmaxf(acc[1] + b2v.y, 0.f) * w3v.y;
            part += fmaxf(acc[2] + b2v.z, 0.f) * w3v.z;
            part += fmaxf(acc[3] + b2v.w, 0.f) * w3v.w;
        }
        part += __shfl_xor(part, 16);
        part += __shfl_xor(part, 32);
        const float logit = act ? part : -1e30f;

        // ---- per-wave softmax partials ----
        m_w = logit;
#pragma unroll
        for (int off = 1; off < 16; off <<= 1)
            m_w = fmaxf(m_w, __shfl_xor(m_w, off));
        ex = act ? __expf(logit - m_w) : 0.f;
        float s_w = ex;
#pragma unroll
        for (int off = 1; off < 16; off <<= 1)
            s_w += __shfl_xor(s_w, off);
        if (l == 0) { mxs[wslot] = m_w; sms[wslot] = s_w; }
    } else {
        if (l == 0) { mxs[wslot] = -1e30f; sms[wslot] = 0.f; }
    }

    __syncthreads();
    const float m = fmaxf(fmaxf(mxs[0], mxs[1]), fmaxf(mxs[2], mxs[3]));
    const float tot = sms[0] * __expf(mxs[0] - m) + sms[1] * __expf(mxs[1] - m)
                    + sms[2] * __expf(mxs[2] - m) + sms[3] * __expf(mxs[3] - m);
    const float scale = live ? __expf(m_w - m) / tot : 0.f;
    if (lg == 0)
        ATT[(size_t)b * 64 + wslot * 16 + lc] = ex * scale;   // 0 for k>=deg
}

// ---------------------------------------------------------------------------
// Kernel 3 (value only, slim): block = one b, wave wslot = k-tile.
// Wide gathers: one float4 load covers 4 k-rows; skip whole 4-k groups
// beyond deg (wave-uniform). LDS reduce across waves.
// ---------------------------------------------------------------------------
__global__ __launch_bounds__(256, 8) void value_kernel(
    const int* __restrict__ history, const int* __restrict__ degrees,
    const float* __restrict__ v_to_e, const float* __restrict__ ATT,
    float* __restrict__ out, int Bn, int K)
{
    __shared__ float red[4][64];

    const int b     = (int)blockIdx.x;
    const int wslot = threadIdx.x >> 6;
    const int l     = threadIdx.x & 63;
    const int lg    = l >> 4;
    const int lc    = l & 15;
    const int deg   = degrees[b];                 // uniform

    int kk = wslot * 16 + lc;
    if (kk > K - 1) kk = K - 1;
    const int vrow = history[(size_t)b * K + kk];            // k_local = lc
    const float att = ATT[(size_t)b * 64 + wslot * 16 + lc]; // 0 beyond deg

    float4 acc4 = {0.f, 0.f, 0.f, 0.f};
#pragma unroll
    for (int jj = 0; jj < 4; ++jj) {
        if (wslot * 16 + jj * 4 < deg) {          // wave-uniform group skip
            const int   row = __shfl(vrow, jj * 4 + lg);
            const float a   = __shfl(att,  jj * 4 + lg);
            const float4 v = *(const float4*)(v_to_e + (size_t)row * D + lc * 4);
            acc4.x += a * v.x;
            acc4.y += a * v.y;
            acc4.z += a * v.z;
            acc4.w += a * v.w;
        }
    }
    // reduce over the 4 k-subgroups (lg axis)
    acc4.x += __shfl_xor(acc4.x, 16); acc4.x += __shfl_xor(acc4.x, 32);
    acc4.y += __shfl_xor(acc4.y, 16); acc4.y += __shfl_xor(acc4.y, 32);
    acc4.z += __shfl_xor(acc4.z, 16); acc4.z += __shfl_xor(acc4.z, 32);
    acc4.w += __shfl_xor(acc4.w, 16); acc4.w += __shfl_xor(acc4.w, 32);

    const float comp = (lg == 0) ? acc4.x : (lg == 1) ? acc4.y
                     : (lg == 2) ? acc4.z : acc4.w;
    red[wslot][lc * 4 + lg] = comp;
    __syncthreads();
    if (wslot == 0)
        out[(size_t)b * D + l] =
            (red[0][l] + red[1][l]) + (red[2][l] + red[3][l]);
}

// ---------------------------------------------------------------------------
// Fallback (no workspace): fused fp32 kernel, one wave per b.
// ---------------------------------------------------------------------------
__global__ __launch_bounds__(256) void agg_fallback(
    const int* __restrict__ nodes, const int* __restrict__ history,
    const int* __restrict__ degrees,
    const float* __restrict__ u_to_e, const float* __restrict__ v_to_e,
    const float* __restrict__ att1_w, const float* __restrict__ att1_b,
    const float* __restrict__ att2_w, const float* __restrict__ att2_b,
    const float* __restrict__ att3_w, const float* __restrict__ att3_b,
    float* __restrict__ out, int Bn, int K)
{
    const int b    = (int)((blockIdx.x * blockDim.x + threadIdx.x) >> 6);
    const int lane = threadIdx.x & 63;
    if (b >= Bn) return;

    const int  deg    = degrees[b];
    const bool active = (lane < deg);
    const int  v      = history[(size_t)b * K + ((lane < K) ? lane : 0)];

    float h1[D];
    float vr[D];
    const float4* v4 = (const float4*)(v_to_e + (size_t)v * D);
#pragma unroll
    for (int i = 0; i < D / 4; ++i) {
        float4 t = v4[i];
        vr[4 * i + 0] = t.x; vr[4 * i + 1] = t.y;
        vr[4 * i + 2] = t.z; vr[4 * i + 3] = t.w;
    }
    const float* urow = u_to_e + (size_t)nodes[b] * D;
#pragma unroll
    for (int d = 0; d < D; ++d) {
        const float* w1 = att1_w + d * TWO_D;
        float a0 = att1_b[d], a1 = 0.f, a2 = 0.f, a3 = 0.f;
#pragma unroll
        for (int f = 0; f < D; f += 4) {
            a0 += vr[f + 0] * w1[f + 0];
            a1 += vr[f + 1] * w1[f + 1];
            a2 += vr[f + 2] * w1[f + 2];
            a3 += vr[f + 3] * w1[f + 3];
            a0 += urow[f + 0] * w1[D + f + 0];
            a1 += urow[f + 1] * w1[D + f + 1];
            a2 += urow[f + 2] * w1[D + f + 2];
            a3 += urow[f + 3] * w1[D + f + 3];
        }
        h1[d] = fmaxf((a0 + a1) + (a2 + a3), 0.f);
    }

    float logit = att3_b[0];
#pragma unroll 4
    for (int e = 0; e < D; ++e) {
        const float* w2r = att2_w + e * D;
        float a0 = 0.f, a1 = 0.f, a2 = 0.f, a3 = 0.f;
#pragma unroll
        for (int dd = 0; dd < D; dd += 4) {
            a0 += h1[dd + 0] * w2r[dd + 0];
            a1 += h1[dd + 1] * w2r[dd + 1];
            a2 += h1[dd + 2] * w2r[dd + 2];
            a3 += h1[dd + 3] * w2r[dd + 3];
        }
        float h2 = (a0 + a1) + (a2 + a3) + att2_b[e];
        logit += fmaxf(h2, 0.f) * att3_w[e];
    }

    float ml = active ? logit : -1e30f;
#pragma unroll
    for (int off = 32; off > 0; off >>= 1) ml = fmaxf(ml, __shfl_xor(ml, off));
    const float ex = active ? __expf(logit - ml) : 0.f;
    float smv = ex;
#pragma unroll
    for (int off = 32; off > 0; off >>= 1) smv += __shfl_xor(smv, off);
    const float att = ex / smv;

    float acc = 0.f;
    for (int kk = 0; kk < deg; ++kk) {
        const float a  = __shfl(att, kk);
        const int   vk = __shfl(v, kk);
        acc += a * v_to_e[(size_t)vk * D + lane];
    }
    out[(size_t)b * D + lane] = acc;
}

// ---------------------------------------------------------------------------
extern "C" void kernel_launch(void* const* d_in, const int* in_sizes, int n_in,
                              void* d_out, int out_size, void* d_ws, size_t ws_size,
                              hipStream_t stream)
{
    const int*   nodes   = (const int*)d_in[0];
    const int*   history = (const int*)d_in[1];
    const int*   degrees = (const int*)d_in[2];
    const float* u_to_e  = (const float*)d_in[3];
    const float* v_to_e  = (const float*)d_in[4];
    const float* att1_w  = (const float*)d_in[5];
    const float* att1_b  = (const float*)d_in[6];
    const float* att2_w  = (const float*)d_in[7];
    const float* att2_b  = (const float*)d_in[8];
    const float* att3_w  = (const float*)d_in[9];
    const float* att3_b  = (const float*)d_in[10];
    float*       out     = (float*)d_out;

    const int Bn = in_sizes[0];
    const int K  = in_sizes[1] / Bn;
    const int NV = in_sizes[4] / D;

    // ws: P16 (bf16 NV*D) | S (fp32 Bn*D) | W2F (8 KB) | ATT (fp32 Bn*64)
    const size_t p16_bytes = (size_t)NV * D * sizeof(unsigned short);
    const size_t s_bytes   = (size_t)Bn * D * sizeof(float);
    const size_t w2f_bytes = (size_t)8 * 64 * 8 * sizeof(unsigned short);
    const size_t att_bytes = (size_t)Bn * 64 * sizeof(float);
    const size_t need = p16_bytes + s_bytes + w2f_bytes + att_bytes;

    if (ws_size >= need) {
        char* p = (char*)d_ws;
        unsigned short* P16 = (unsigned short*)p;            p += p16_bytes;
        float*          S   = (float*)p;                     p += s_bytes;
        unsigned short* W2F = (unsigned short*)p;            p += w2f_bytes;
        float*          ATT = (float*)p;
        const int nPB = (NV + 63) / 64;
        const int nSB = (Bn + 63) / 64;
        proj_gemm<<<nPB + nSB + 1, 256, 0, stream>>>(
            v_to_e, u_to_e, nodes, att1_w, att1_b, att2_w,
            P16, S, W2F, NV, Bn, nPB);
        score_mfma<<<Bn, 256, 0, stream>>>(
            history, degrees, att2_b, att3_w,
            P16, S, W2F, ATT, Bn, K);
        value_kernel<<<Bn, 256, 0, stream>>>(
            history, degrees, v_to_e, ATT, out, Bn, K);
    } else {
        const int agg_blocks = (Bn * 64 + 255) / 256;
        agg_fallback<<<agg_blocks, 256, 0, stream>>>(
            nodes, history, degrees, u_to_e, v_to_e,
            att1_w, att1_b, att2_w, att2_b, att3_w, att3_b,
            out, Bn, K);
    }
}

// Round 12
// 52.277 us; speedup vs baseline: 1.1041x; 1.1041x over previous
//
#include <hip/hip_runtime.h>
#include <cstdint>
#include <cstddef>

constexpr int D = 64;
constexpr int TWO_D = 128;

typedef __attribute__((ext_vector_type(8))) short bf16x8;
typedef __attribute__((ext_vector_type(4))) float f32x4;
typedef __attribute__((ext_vector_type(4))) unsigned short u16x4;

static __device__ __forceinline__ short f2bf(float x) {
    unsigned u = __builtin_bit_cast(unsigned, x);
    u += 0x7fffu + ((u >> 16) & 1u);          // round-to-nearest-even
    return (short)(u >> 16);
}
static __device__ __forceinline__ float bf2f(short h) {
    return __builtin_bit_cast(float, ((unsigned)(unsigned short)h) << 16);
}
static __device__ __forceinline__ bf16x8 cvt8(const float* p) {
    const float4 a = *(const float4*)p;
    const float4 c = *(const float4*)(p + 4);
    bf16x8 f;
    f[0] = f2bf(a.x); f[1] = f2bf(a.y); f[2] = f2bf(a.z); f[3] = f2bf(a.w);
    f[4] = f2bf(c.x); f[5] = f2bf(c.y); f[6] = f2bf(c.z); f[7] = f2bf(c.w);
    return f;
}

// ---------------------------------------------------------------------------
// Kernel 1 (MFMA, zero LDS): projection tables.
//   blocks [0, nPB):        P16[r,:] = bf16( v_to_e[r,:] . att1_w[:,0:D]^T )
//   blocks [nPB, nPB+nSB):  S[b,:]   = u_to_e[nodes[b],:] . att1_w[:,D:2D]^T + b1
//   block  nPB+nSB:         W2F = bf16 MFMA A-fragments of W2 (for agg launch)
// Per block: 4 waves x 16 rows. A = x rows straight from global (bf16 cvt),
// B = W1 fragments from L1-hot att1_w. D stored directly; no __shared__.
// MFMA frag layout (validated by passing R4-R10 kernels):
//   A/B elem j of lane l -> (idx16 = l&15, k = ks*32 + (l>>4)*8 + j)
//   D  reg r of lane l  -> row (l>>4)*4 + r, col l&15
// ---------------------------------------------------------------------------
__global__ __launch_bounds__(256) void proj_mfma(
    const float* __restrict__ v_to_e, const float* __restrict__ u_to_e,
    const int* __restrict__ nodes,
    const float* __restrict__ att1_w, const float* __restrict__ att1_b,
    const float* __restrict__ att2_w,
    unsigned short* __restrict__ P16, float* __restrict__ S,
    unsigned short* __restrict__ W2F,
    int NV, int Bn, int nPB)
{
    const int tid = threadIdx.x;

    if ((int)blockIdx.x == nPB + (Bn + 63) / 64) {   // W2 pack block
        if (tid < 64) {
            const int plg = tid >> 4, plc = tid & 15;
#pragma unroll
            for (int tc = 0; tc < 4; ++tc)
#pragma unroll
                for (int ks = 0; ks < 2; ++ks) {
                    const bf16x8 f =
                        cvt8(att2_w + (tc * 16 + plc) * D + ks * 32 + plg * 8);
                    *(bf16x8*)(W2F + ((size_t)(tc * 2 + ks) * 64 + tid) * 8) = f;
                }
        }
        return;
    }

    const bool isS = ((int)blockIdx.x >= nPB);
    const int base = (isS ? ((int)blockIdx.x - nPB) : (int)blockIdx.x) * 64;
    const int nRows = isS ? Bn : NV;
    const int woff  = isS ? D : 0;
    const float* X  = isS ? u_to_e : v_to_e;

    const int w  = tid >> 6;     // wave: rows [base+w*16, base+w*16+16)
    const int l  = tid & 63;
    const int lg = l >> 4;
    const int lc = l & 15;

    // ---- B operand: W1 fragments (att1_w is 32KB, L1-hot) ----
    bf16x8 w1f[4][2];
#pragma unroll
    for (int tc = 0; tc < 4; ++tc)
#pragma unroll
        for (int ks = 0; ks < 2; ++ks)
            w1f[tc][ks] = cvt8(
                att1_w + (tc * 16 + lc) * TWO_D + woff + ks * 32 + lg * 8);

    // ---- A operand: x row for this lane (one visit, coalesced) ----
    int grow = base + w * 16 + lc;
    if (grow >= nRows) grow = nRows - 1;             // tail clamp
    const int xrow = isS ? nodes[grow] : grow;
    const float* xp = X + (size_t)xrow * D;
    bf16x8 a0 = cvt8(xp + lg * 8);                   // k = 0..31 slice
    bf16x8 a1 = cvt8(xp + 32 + lg * 8);              // k = 32..63 slice

    // ---- MFMA: acc[tc] = A x W1^T ----
    f32x4 acc[4];
#pragma unroll
    for (int tc = 0; tc < 4; ++tc) acc[tc] = (f32x4)0.f;
#pragma unroll
    for (int tc = 0; tc < 4; ++tc) {
        acc[tc] = __builtin_amdgcn_mfma_f32_16x16x32_bf16(a0, w1f[tc][0], acc[tc], 0, 0, 0);
        acc[tc] = __builtin_amdgcn_mfma_f32_16x16x32_bf16(a1, w1f[tc][1], acc[tc], 0, 0, 0);
    }

    // ---- store D: lane l reg r -> row base+w*16+lg*4+r, col tc*16+lc ----
    if (isS) {
#pragma unroll
        for (int r = 0; r < 4; ++r) {
            const int gr = base + w * 16 + lg * 4 + r;
            if (gr < nRows) {
#pragma unroll
                for (int tc = 0; tc < 4; ++tc)
                    S[(size_t)gr * D + tc * 16 + lc] =
                        acc[tc][r] + att1_b[tc * 16 + lc];
            }
        }
    } else {
#pragma unroll
        for (int r = 0; r < 4; ++r) {
            const int gr = base + w * 16 + lg * 4 + r;
            if (gr < nRows) {
#pragma unroll
                for (int tc = 0; tc < 4; ++tc)
                    P16[(size_t)gr * D + tc * 16 + lc] =
                        (unsigned short)f2bf(acc[tc][r]);
            }
        }
    }
}

// ---------------------------------------------------------------------------
// Kernel 2 (MFMA, 4 waves per b): R10 structure (best agg, 36 us).
// Value path: one float4 load covers FOUR k-rows; weights via __shfl.
// Flash-style softmax; value gathers issued at kernel top (overlap!).
// ---------------------------------------------------------------------------
__global__ __launch_bounds__(256) void agg_mfma(
    const int* __restrict__ history, const int* __restrict__ degrees,
    const float* __restrict__ v_to_e,
    const float* __restrict__ att2_b, const float* __restrict__ att3_w,
    const unsigned short* __restrict__ P16, const float* __restrict__ S,
    const unsigned short* __restrict__ W2F,
    float* __restrict__ out, int Bn, int K)
{
    __shared__ float red[4][64];
    __shared__ float mxs[4];
    __shared__ float sms[4];

    const int b     = (int)blockIdx.x;
    const int wslot = threadIdx.x >> 6;
    const int l     = threadIdx.x & 63;
    const int lg    = l >> 4;
    const int lc    = l & 15;
    const int deg   = degrees[b];                 // uniform
    const bool live = (wslot * 16 < deg);         // wave-uniform
    const bool act  = (wslot * 16 + lc < deg);

    int kk = wslot * 16 + lc;
    if (kk > K - 1) kk = K - 1;
    const int vrow = history[(size_t)b * K + kk];   // row id for k_local = lc

    // ---- prefetch value rows: 4 wide loads, each covering 4 rows ----
    float4 vr4[4];
    if (live) {
#pragma unroll
        for (int jj = 0; jj < 4; ++jj) {
            const int row = __shfl(vrow, jj * 4 + lg);
            vr4[jj] = *(const float4*)(v_to_e + (size_t)row * D + lc * 4);
        }
    }

    float m_w = -1e30f, ex = 0.f;
    float4 acc4 = {0.f, 0.f, 0.f, 0.f};
    if (live) {
        // ---- h1 fragment: P16 gather + S row ----
        const bf16x8 praw0 = *(const bf16x8*)(P16 + (size_t)vrow * D + lg * 8);
        const bf16x8 praw1 = *(const bf16x8*)(P16 + (size_t)vrow * D + 32 + lg * 8);
        const float* sp = S + (size_t)b * D;
        const float4 s00 = *(const float4*)(sp + lg * 8);
        const float4 s01 = *(const float4*)(sp + lg * 8 + 4);
        const float4 s10 = *(const float4*)(sp + 32 + lg * 8);
        const float4 s11 = *(const float4*)(sp + 32 + lg * 8 + 4);

        bf16x8 af0, af1;
        af0[0] = f2bf(fmaxf(bf2f(praw0[0]) + s00.x, 0.f));
        af0[1] = f2bf(fmaxf(bf2f(praw0[1]) + s00.y, 0.f));
        af0[2] = f2bf(fmaxf(bf2f(praw0[2]) + s00.z, 0.f));
        af0[3] = f2bf(fmaxf(bf2f(praw0[3]) + s00.w, 0.f));
        af0[4] = f2bf(fmaxf(bf2f(praw0[4]) + s01.x, 0.f));
        af0[5] = f2bf(fmaxf(bf2f(praw0[5]) + s01.y, 0.f));
        af0[6] = f2bf(fmaxf(bf2f(praw0[6]) + s01.z, 0.f));
        af0[7] = f2bf(fmaxf(bf2f(praw0[7]) + s01.w, 0.f));
        af1[0] = f2bf(fmaxf(bf2f(praw1[0]) + s10.x, 0.f));
        af1[1] = f2bf(fmaxf(bf2f(praw1[1]) + s10.y, 0.f));
        af1[2] = f2bf(fmaxf(bf2f(praw1[2]) + s10.z, 0.f));
        af1[3] = f2bf(fmaxf(bf2f(praw1[3]) + s10.w, 0.f));
        af1[4] = f2bf(fmaxf(bf2f(praw1[4]) + s11.x, 0.f));
        af1[5] = f2bf(fmaxf(bf2f(praw1[5]) + s11.y, 0.f));
        af1[6] = f2bf(fmaxf(bf2f(praw1[6]) + s11.z, 0.f));
        af1[7] = f2bf(fmaxf(bf2f(praw1[7]) + s11.w, 0.f));

        // ---- transposed MFMA: acc[tc] = W2_frag x h1^T ----
        f32x4 acc[4];
#pragma unroll
        for (int tc = 0; tc < 4; ++tc) acc[tc] = (f32x4)0.f;
#pragma unroll
        for (int tc = 0; tc < 4; ++tc) {
            const bf16x8 w0 = *(const bf16x8*)(
                W2F + ((size_t)(tc * 2 + 0) * 64 + l) * 8);
            acc[tc] = __builtin_amdgcn_mfma_f32_16x16x32_bf16(
                w0, af0, acc[tc], 0, 0, 0);
            const bf16x8 w1 = *(const bf16x8*)(
                W2F + ((size_t)(tc * 2 + 1) * 64 + l) * 8);
            acc[tc] = __builtin_amdgcn_mfma_f32_16x16x32_bf16(
                w1, af1, acc[tc], 0, 0, 0);
        }

        // ---- epilogue: logit[k=lc] = sum_e relu(H2+b2)*w3, e=tc*16+lg*4+r --
        float part = 0.f;
#pragma unroll
        for (int tc = 0; tc < 4; ++tc) {
            const float4 b2v = *(const float4*)(att2_b + tc * 16 + lg * 4);
            const float4 w3v = *(const float4*)(att3_w + tc * 16 + lg * 4);
            part += fmaxf(acc[tc][0] + b2v.x, 0.f) * w3v.x;
            part += fmaxf(acc[tc][1] + b2v.y, 0.f) * w3v.y;
            part += fmaxf(acc[tc][2] + b2v.z, 0.f) * w3v.z;
            part += fmaxf(acc[tc][3] + b2v.w, 0.f) * w3v.w;
        }
        part += __shfl_xor(part, 16);
        part += __shfl_xor(part, 32);
        const float logit = act ? part : -1e30f;

        // ---- per-wave softmax partials (flash style) ----
        m_w = logit;
#pragma unroll
        for (int off = 1; off < 16; off <<= 1)
            m_w = fmaxf(m_w, __shfl_xor(m_w, off));
        ex = act ? __expf(logit - m_w) : 0.f;
        float s_w = ex;
#pragma unroll
        for (int off = 1; off < 16; off <<= 1)
            s_w += __shfl_xor(s_w, off);
        if (l == 0) { mxs[wslot] = m_w; sms[wslot] = s_w; }

        // ---- value FMA with unnormalized weights (before barrier) ----
#pragma unroll
        for (int jj = 0; jj < 4; ++jj) {
            const float a = __shfl(ex, jj * 4 + lg);
            acc4.x += a * vr4[jj].x;
            acc4.y += a * vr4[jj].y;
            acc4.z += a * vr4[jj].z;
            acc4.w += a * vr4[jj].w;
        }
        acc4.x += __shfl_xor(acc4.x, 16); acc4.x += __shfl_xor(acc4.x, 32);
        acc4.y += __shfl_xor(acc4.y, 16); acc4.y += __shfl_xor(acc4.y, 32);
        acc4.z += __shfl_xor(acc4.z, 16); acc4.z += __shfl_xor(acc4.z, 32);
        acc4.w += __shfl_xor(acc4.w, 16); acc4.w += __shfl_xor(acc4.w, 32);
    } else {
        if (l == 0) { mxs[wslot] = -1e30f; sms[wslot] = 0.f; }
    }

    __syncthreads();
    const float m = fmaxf(fmaxf(mxs[0], mxs[1]), fmaxf(mxs[2], mxs[3]));
    const float tot = sms[0] * __expf(mxs[0] - m) + sms[1] * __expf(mxs[1] - m)
                    + sms[2] * __expf(mxs[2] - m) + sms[3] * __expf(mxs[3] - m);
    const float scale = live ? __expf(m_w - m) / tot : 0.f;

    const float comp = (lg == 0) ? acc4.x : (lg == 1) ? acc4.y
                     : (lg == 2) ? acc4.z : acc4.w;
    red[wslot][lc * 4 + lg] = comp * scale;
    __syncthreads();
    if (wslot == 0)
        out[(size_t)b * D + l] =
            (red[0][l] + red[1][l]) + (red[2][l] + red[3][l]);
}

// ---------------------------------------------------------------------------
// Fallback (no workspace): fused fp32 kernel, one wave per b.
// ---------------------------------------------------------------------------
__global__ __launch_bounds__(256) void agg_fallback(
    const int* __restrict__ nodes, const int* __restrict__ history,
    const int* __restrict__ degrees,
    const float* __restrict__ u_to_e, const float* __restrict__ v_to_e,
    const float* __restrict__ att1_w, const float* __restrict__ att1_b,
    const float* __restrict__ att2_w, const float* __restrict__ att2_b,
    const float* __restrict__ att3_w, const float* __restrict__ att3_b,
    float* __restrict__ out, int Bn, int K)
{
    const int b    = (int)((blockIdx.x * blockDim.x + threadIdx.x) >> 6);
    const int lane = threadIdx.x & 63;
    if (b >= Bn) return;

    const int  deg    = degrees[b];
    const bool active = (lane < deg);
    const int  v      = history[(size_t)b * K + ((lane < K) ? lane : 0)];

    float h1[D];
    float vr[D];
    const float4* v4 = (const float4*)(v_to_e + (size_t)v * D);
#pragma unroll
    for (int i = 0; i < D / 4; ++i) {
        float4 t = v4[i];
        vr[4 * i + 0] = t.x; vr[4 * i + 1] = t.y;
        vr[4 * i + 2] = t.z; vr[4 * i + 3] = t.w;
    }
    const float* urow = u_to_e + (size_t)nodes[b] * D;
#pragma unroll
    for (int d = 0; d < D; ++d) {
        const float* w1 = att1_w + d * TWO_D;
        float a0 = att1_b[d], a1 = 0.f, a2 = 0.f, a3 = 0.f;
#pragma unroll
        for (int f = 0; f < D; f += 4) {
            a0 += vr[f + 0] * w1[f + 0];
            a1 += vr[f + 1] * w1[f + 1];
            a2 += vr[f + 2] * w1[f + 2];
            a3 += vr[f + 3] * w1[f + 3];
            a0 += urow[f + 0] * w1[D + f + 0];
            a1 += urow[f + 1] * w1[D + f + 1];
            a2 += urow[f + 2] * w1[D + f + 2];
            a3 += urow[f + 3] * w1[D + f + 3];
        }
        h1[d] = fmaxf((a0 + a1) + (a2 + a3), 0.f);
    }

    float logit = att3_b[0];
#pragma unroll 4
    for (int e = 0; e < D; ++e) {
        const float* w2r = att2_w + e * D;
        float a0 = 0.f, a1 = 0.f, a2 = 0.f, a3 = 0.f;
#pragma unroll
        for (int dd = 0; dd < D; dd += 4) {
            a0 += h1[dd + 0] * w2r[dd + 0];
            a1 += h1[dd + 1] * w2r[dd + 1];
            a2 += h1[dd + 2] * w2r[dd + 2];
            a3 += h1[dd + 3] * w2r[dd + 3];
        }
        float h2 = (a0 + a1) + (a2 + a3) + att2_b[e];
        logit += fmaxf(h2, 0.f) * att3_w[e];
    }

    float ml = active ? logit : -1e30f;
#pragma unroll
    for (int off = 32; off > 0; off >>= 1) ml = fmaxf(ml, __shfl_xor(ml, off));
    const float ex = active ? __expf(logit - ml) : 0.f;
    float smv = ex;
#pragma unroll
    for (int off = 32; off > 0; off >>= 1) smv += __shfl_xor(smv, off);
    const float att = ex / smv;

    float acc = 0.f;
    for (int kk = 0; kk < deg; ++kk) {
        const float a  = __shfl(att, kk);
        const int   vk = __shfl(v, kk);
        acc += a * v_to_e[(size_t)vk * D + lane];
    }
    out[(size_t)b * D + lane] = acc;
}

// ---------------------------------------------------------------------------
extern "C" void kernel_launch(void* const* d_in, const int* in_sizes, int n_in,
                              void* d_out, int out_size, void* d_ws, size_t ws_size,
                              hipStream_t stream)
{
    const int*   nodes   = (const int*)d_in[0];
    const int*   history = (const int*)d_in[1];
    const int*   degrees = (const int*)d_in[2];
    const float* u_to_e  = (const float*)d_in[3];
    const float* v_to_e  = (const float*)d_in[4];
    const float* att1_w  = (const float*)d_in[5];
    const float* att1_b  = (const float*)d_in[6];
    const float* att2_w  = (const float*)d_in[7];
    const float* att2_b  = (const float*)d_in[8];
    const float* att3_w  = (const float*)d_in[9];
    const float* att3_b  = (const float*)d_in[10];
    float*       out     = (float*)d_out;

    const int Bn = in_sizes[0];
    const int K  = in_sizes[1] / Bn;
    const int NV = in_sizes[4] / D;

    // workspace: P16 (bf16 NV*D) | S (fp32 Bn*D) | W2F (8 KB)
    const size_t p16_bytes = (size_t)NV * D * sizeof(unsigned short);
    const size_t s_bytes   = (size_t)Bn * D * sizeof(float);
    const size_t w2f_bytes = (size_t)8 * 64 * 8 * sizeof(unsigned short);
    const size_t need = p16_bytes + s_bytes + w2f_bytes;

    if (ws_size >= need) {
        unsigned short* P16 = (unsigned short*)d_ws;
        float* S = (float*)((char*)d_ws + p16_bytes);
        unsigned short* W2F = (unsigned short*)((char*)d_ws + p16_bytes + s_bytes);
        const int nPB = (NV + 63) / 64;
        const int nSB = (Bn + 63) / 64;
        proj_mfma<<<nPB + nSB + 1, 256, 0, stream>>>(
            v_to_e, u_to_e, nodes, att1_w, att1_b, att2_w,
            P16, S, W2F, NV, Bn, nPB);
        agg_mfma<<<Bn, 256, 0, stream>>>(
            history, degrees, v_to_e, att2_b, att3_w,
            P16, S, W2F, out, Bn, K);
    } else {
        const int agg_blocks = (Bn * 64 + 255) / 256;
        agg_fallback<<<agg_blocks, 256, 0, stream>>>(
            nodes, history, degrees, u_to_e, v_to_e,
            att1_w, att1_b, att2_w, att2_b, att3_w, att3_b,
            out, Bn, K);
    }
}

// Round 13
// 51.766 us; speedup vs baseline: 1.1150x; 1.0099x over previous
//
#include <hip/hip_runtime.h>
#include <cstdint>
#include <cstddef>

constexpr int D = 64;
constexpr int TWO_D = 128;

typedef __attribute__((ext_vector_type(8))) short bf16x8;
typedef __attribute__((ext_vector_type(4))) float f32x4;
typedef __attribute__((ext_vector_type(4))) unsigned short u16x4;

static __device__ __forceinline__ short f2bf(float x) {
    unsigned u = __builtin_bit_cast(unsigned, x);
    u += 0x7fffu + ((u >> 16) & 1u);          // round-to-nearest-even
    return (short)(u >> 16);
}
static __device__ __forceinline__ float bf2f(unsigned short h) {
    return __builtin_bit_cast(float, ((unsigned)h) << 16);
}

// ---------------------------------------------------------------------------
// Kernel 1: projection tables, tiled fp32 GEMM + W2 pack (R8 version, proven).
//   blocks [0, nPB):        P16[r,:] = bf16( v_to_e[r,:] . att1_w[:,0:D]^T )
//                           V16[r,:] = bf16( v_to_e[r,:] )  (emitted in staging)
//   blocks [nPB, nPB+nSB):  S[b,:]   = u_to_e[nodes[b],:] . att1_w[:,D:2D]^T + b1
//   block  nPB+nSB:         W2F = bf16 MFMA A-fragments of W2
// ---------------------------------------------------------------------------
__global__ __launch_bounds__(256) void proj_gemm(
    const float* __restrict__ v_to_e, const float* __restrict__ u_to_e,
    const int* __restrict__ nodes,
    const float* __restrict__ att1_w, const float* __restrict__ att1_b,
    const float* __restrict__ att2_w,
    unsigned short* __restrict__ P16, float* __restrict__ S,
    unsigned short* __restrict__ W2F, unsigned short* __restrict__ V16,
    int NV, int Bn, int nPB)
{
    const int tid = threadIdx.x;

    if ((int)blockIdx.x == nPB + (Bn + 63) / 64) {   // W2 pack block
        if (tid < 64) {
            const int plg = tid >> 4, plc = tid & 15;
#pragma unroll
            for (int tc = 0; tc < 4; ++tc)
#pragma unroll
                for (int ks = 0; ks < 2; ++ks) {
                    const float* src =
                        att2_w + (tc * 16 + plc) * D + ks * 32 + plg * 8;
                    const float4 a = *(const float4*)src;
                    const float4 c = *(const float4*)(src + 4);
                    bf16x8 f;
                    f[0] = f2bf(a.x); f[1] = f2bf(a.y);
                    f[2] = f2bf(a.z); f[3] = f2bf(a.w);
                    f[4] = f2bf(c.x); f[5] = f2bf(c.y);
                    f[6] = f2bf(c.z); f[7] = f2bf(c.w);
                    *(bf16x8*)(W2F + ((size_t)(tc * 2 + ks) * 64 + tid) * 8) = f;
                }
        }
        return;
    }

    constexpr int ST = 68;
    __shared__ float xs[64 * ST];
    __shared__ float ws[64 * ST];

    const bool isS = ((int)blockIdx.x >= nPB);
    const int base = (isS ? ((int)blockIdx.x - nPB) : (int)blockIdx.x) * 64;
    const int nRows = isS ? Bn : NV;
    const int woff  = isS ? D : 0;
    const float* X  = isS ? u_to_e : v_to_e;

#pragma unroll
    for (int it = 0; it < 4; ++it) {
        const int flat = it * 256 + tid;
        const int dd = flat >> 4, f4 = flat & 15;
        const float4 w = *(const float4*)(att1_w + dd * TWO_D + woff + f4 * 4);
        ws[(f4 * 4 + 0) * ST + dd] = w.x;
        ws[(f4 * 4 + 1) * ST + dd] = w.y;
        ws[(f4 * 4 + 2) * ST + dd] = w.z;
        ws[(f4 * 4 + 3) * ST + dd] = w.w;
    }
#pragma unroll
    for (int it = 0; it < 4; ++it) {
        const int flat = it * 256 + tid;
        const int r = flat >> 4, f4 = flat & 15;
        int gr = base + r;
        if (gr >= nRows) gr = nRows - 1;
        const int row = isS ? nodes[gr] : gr;
        const float4 x = *(const float4*)(X + (size_t)row * D + f4 * 4);
        xs[(f4 * 4 + 0) * ST + r] = x.x;
        xs[(f4 * 4 + 1) * ST + r] = x.y;
        xs[(f4 * 4 + 2) * ST + r] = x.z;
        xs[(f4 * 4 + 3) * ST + r] = x.w;
        if (!isS) {
            u16x4 o;
            o[0] = (unsigned short)f2bf(x.x);
            o[1] = (unsigned short)f2bf(x.y);
            o[2] = (unsigned short)f2bf(x.z);
            o[3] = (unsigned short)f2bf(x.w);
            *(u16x4*)(V16 + (size_t)gr * D + f4 * 4) = o;
        }
    }
    __syncthreads();

    const int d0 = (tid & 15) * 4;
    const int r0 = (tid >> 4) * 4;
    float acc[4][4];
#pragma unroll
    for (int i = 0; i < 4; ++i)
#pragma unroll
        for (int j = 0; j < 4; ++j) acc[i][j] = 0.f;

#pragma unroll 8
    for (int f = 0; f < D; ++f) {
        const float4 w = *(const float4*)&ws[f * ST + d0];
        const float4 x = *(const float4*)&xs[f * ST + r0];
        const float wv[4] = {w.x, w.y, w.z, w.w};
        const float xv[4] = {x.x, x.y, x.z, x.w};
#pragma unroll
        for (int ri = 0; ri < 4; ++ri)
#pragma unroll
            for (int di = 0; di < 4; ++di)
                acc[ri][di] += xv[ri] * wv[di];
    }

    if (isS) {
        float bv[4];
#pragma unroll
        for (int di = 0; di < 4; ++di) bv[di] = att1_b[d0 + di];
#pragma unroll
        for (int ri = 0; ri < 4; ++ri) {
            const int gr = base + r0 + ri;
            if (gr < nRows) {
                float4 o = {acc[ri][0] + bv[0], acc[ri][1] + bv[1],
                            acc[ri][2] + bv[2], acc[ri][3] + bv[3]};
                *(float4*)(S + (size_t)gr * D + d0) = o;
            }
        }
    } else {
#pragma unroll
        for (int ri = 0; ri < 4; ++ri) {
            const int gr = base + r0 + ri;
            if (gr < nRows) {
                u16x4 o;
                o[0] = (unsigned short)f2bf(acc[ri][0]);
                o[1] = (unsigned short)f2bf(acc[ri][1]);
                o[2] = (unsigned short)f2bf(acc[ri][2]);
                o[3] = (unsigned short)f2bf(acc[ri][3]);
                *(u16x4*)(P16 + (size_t)gr * D + d0) = o;
            }
        }
    }
}

// ---------------------------------------------------------------------------
// Kernel 2 (MFMA, 4 waves per b, SLIM for 8 waves/SIMD):
//  - value prefetch from bf16 V16 (8B/lane, 8 VGPR instead of 16)
//  - single-accumulator tc loop with fused epilogue (4 VGPR instead of 16)
//  - flash softmax + wide value FMA (R10 mapping) unchanged
// ---------------------------------------------------------------------------
__global__ __launch_bounds__(256, 8) void agg_mfma(
    const int* __restrict__ history, const int* __restrict__ degrees,
    const float* __restrict__ att2_b, const float* __restrict__ att3_w,
    const unsigned short* __restrict__ P16, const float* __restrict__ S,
    const unsigned short* __restrict__ W2F,
    const unsigned short* __restrict__ V16,
    float* __restrict__ out, int Bn, int K)
{
    __shared__ float red[4][64];
    __shared__ float mxs[4];
    __shared__ float sms[4];

    const int b     = (int)blockIdx.x;
    const int wslot = threadIdx.x >> 6;
    const int l     = threadIdx.x & 63;
    const int lg    = l >> 4;
    const int lc    = l & 15;
    const int deg   = degrees[b];                 // uniform
    const bool live = (wslot * 16 < deg);         // wave-uniform
    const bool act  = (wslot * 16 + lc < deg);

    int kk = wslot * 16 + lc;
    if (kk > K - 1) kk = K - 1;
    const int vrow = history[(size_t)b * K + kk];   // row id for k_local = lc

    // ---- prefetch value rows from V16: 4 x 8B loads (4 rows each) ----
    u16x4 vr4[4];
    if (live) {
#pragma unroll
        for (int jj = 0; jj < 4; ++jj) {
            const int row = __shfl(vrow, jj * 4 + lg);
            vr4[jj] = *(const u16x4*)(V16 + (size_t)row * D + lc * 4);
        }
    }

    float m_w = -1e30f, ex = 0.f;
    float4 acc4 = {0.f, 0.f, 0.f, 0.f};
    if (live) {
        // ---- h1 fragment: P16 gather + S row ----
        const bf16x8 praw0 = *(const bf16x8*)(P16 + (size_t)vrow * D + lg * 8);
        const bf16x8 praw1 = *(const bf16x8*)(P16 + (size_t)vrow * D + 32 + lg * 8);
        const float* sp = S + (size_t)b * D;
        const float4 s00 = *(const float4*)(sp + lg * 8);
        const float4 s01 = *(const float4*)(sp + lg * 8 + 4);
        const float4 s10 = *(const float4*)(sp + 32 + lg * 8);
        const float4 s11 = *(const float4*)(sp + 32 + lg * 8 + 4);

        bf16x8 af0, af1;
        af0[0] = f2bf(fmaxf(bf2f((unsigned short)praw0[0]) + s00.x, 0.f));
        af0[1] = f2bf(fmaxf(bf2f((unsigned short)praw0[1]) + s00.y, 0.f));
        af0[2] = f2bf(fmaxf(bf2f((unsigned short)praw0[2]) + s00.z, 0.f));
        af0[3] = f2bf(fmaxf(bf2f((unsigned short)praw0[3]) + s00.w, 0.f));
        af0[4] = f2bf(fmaxf(bf2f((unsigned short)praw0[4]) + s01.x, 0.f));
        af0[5] = f2bf(fmaxf(bf2f((unsigned short)praw0[5]) + s01.y, 0.f));
        af0[6] = f2bf(fmaxf(bf2f((unsigned short)praw0[6]) + s01.z, 0.f));
        af0[7] = f2bf(fmaxf(bf2f((unsigned short)praw0[7]) + s01.w, 0.f));
        af1[0] = f2bf(fmaxf(bf2f((unsigned short)praw1[0]) + s10.x, 0.f));
        af1[1] = f2bf(fmaxf(bf2f((unsigned short)praw1[1]) + s10.y, 0.f));
        af1[2] = f2bf(fmaxf(bf2f((unsigned short)praw1[2]) + s10.z, 0.f));
        af1[3] = f2bf(fmaxf(bf2f((unsigned short)praw1[3]) + s10.w, 0.f));
        af1[4] = f2bf(fmaxf(bf2f((unsigned short)praw1[4]) + s11.x, 0.f));
        af1[5] = f2bf(fmaxf(bf2f((unsigned short)praw1[5]) + s11.y, 0.f));
        af1[6] = f2bf(fmaxf(bf2f((unsigned short)praw1[6]) + s11.z, 0.f));
        af1[7] = f2bf(fmaxf(bf2f((unsigned short)praw1[7]) + s11.w, 0.f));

        // ---- per-tc MFMA + fused epilogue (single live accumulator) ----
        float part = 0.f;
#pragma unroll
        for (int tc = 0; tc < 4; ++tc) {
            f32x4 acc = (f32x4)0.f;
            const bf16x8 w0 = *(const bf16x8*)(
                W2F + ((size_t)(tc * 2 + 0) * 64 + l) * 8);
            acc = __builtin_amdgcn_mfma_f32_16x16x32_bf16(w0, af0, acc, 0, 0, 0);
            const bf16x8 w1 = *(const bf16x8*)(
                W2F + ((size_t)(tc * 2 + 1) * 64 + l) * 8);
            acc = __builtin_amdgcn_mfma_f32_16x16x32_bf16(w1, af1, acc, 0, 0, 0);
            const float4 b2v = *(const float4*)(att2_b + tc * 16 + lg * 4);
            const float4 w3v = *(const float4*)(att3_w + tc * 16 + lg * 4);
            part += fmaxf(acc[0] + b2v.x, 0.f) * w3v.x;
            part += fmaxf(acc[1] + b2v.y, 0.f) * w3v.y;
            part += fmaxf(acc[2] + b2v.z, 0.f) * w3v.z;
            part += fmaxf(acc[3] + b2v.w, 0.f) * w3v.w;
        }
        part += __shfl_xor(part, 16);
        part += __shfl_xor(part, 32);
        const float logit = act ? part : -1e30f;

        // ---- per-wave softmax partials (flash style) ----
        m_w = logit;
#pragma unroll
        for (int off = 1; off < 16; off <<= 1)
            m_w = fmaxf(m_w, __shfl_xor(m_w, off));
        ex = act ? __expf(logit - m_w) : 0.f;
        float s_w = ex;
#pragma unroll
        for (int off = 1; off < 16; off <<= 1)
            s_w += __shfl_xor(s_w, off);
        if (l == 0) { mxs[wslot] = m_w; sms[wslot] = s_w; }

        // ---- value FMA with unnormalized weights (before barrier) ----
#pragma unroll
        for (int jj = 0; jj < 4; ++jj) {
            const float a = __shfl(ex, jj * 4 + lg);
            acc4.x += a * bf2f(vr4[jj][0]);
            acc4.y += a * bf2f(vr4[jj][1]);
            acc4.z += a * bf2f(vr4[jj][2]);
            acc4.w += a * bf2f(vr4[jj][3]);
        }
        acc4.x += __shfl_xor(acc4.x, 16); acc4.x += __shfl_xor(acc4.x, 32);
        acc4.y += __shfl_xor(acc4.y, 16); acc4.y += __shfl_xor(acc4.y, 32);
        acc4.z += __shfl_xor(acc4.z, 16); acc4.z += __shfl_xor(acc4.z, 32);
        acc4.w += __shfl_xor(acc4.w, 16); acc4.w += __shfl_xor(acc4.w, 32);
    } else {
        if (l == 0) { mxs[wslot] = -1e30f; sms[wslot] = 0.f; }
    }

    __syncthreads();
    const float m = fmaxf(fmaxf(mxs[0], mxs[1]), fmaxf(mxs[2], mxs[3]));
    const float tot = sms[0] * __expf(mxs[0] - m) + sms[1] * __expf(mxs[1] - m)
                    + sms[2] * __expf(mxs[2] - m) + sms[3] * __expf(mxs[3] - m);
    const float scale = live ? __expf(m_w - m) / tot : 0.f;

    const float comp = (lg == 0) ? acc4.x : (lg == 1) ? acc4.y
                     : (lg == 2) ? acc4.z : acc4.w;
    red[wslot][lc * 4 + lg] = comp * scale;
    __syncthreads();
    if (wslot == 0)
        out[(size_t)b * D + l] =
            (red[0][l] + red[1][l]) + (red[2][l] + red[3][l]);
}

// ---------------------------------------------------------------------------
// Fallback (no workspace): fused fp32 kernel, one wave per b.
// ---------------------------------------------------------------------------
__global__ __launch_bounds__(256) void agg_fallback(
    const int* __restrict__ nodes, const int* __restrict__ history,
    const int* __restrict__ degrees,
    const float* __restrict__ u_to_e, const float* __restrict__ v_to_e,
    const float* __restrict__ att1_w, const float* __restrict__ att1_b,
    const float* __restrict__ att2_w, const float* __restrict__ att2_b,
    const float* __restrict__ att3_w, const float* __restrict__ att3_b,
    float* __restrict__ out, int Bn, int K)
{
    const int b    = (int)((blockIdx.x * blockDim.x + threadIdx.x) >> 6);
    const int lane = threadIdx.x & 63;
    if (b >= Bn) return;

    const int  deg    = degrees[b];
    const bool active = (lane < deg);
    const int  v      = history[(size_t)b * K + ((lane < K) ? lane : 0)];

    float h1[D];
    float vr[D];
    const float4* v4 = (const float4*)(v_to_e + (size_t)v * D);
#pragma unroll
    for (int i = 0; i < D / 4; ++i) {
        float4 t = v4[i];
        vr[4 * i + 0] = t.x; vr[4 * i + 1] = t.y;
        vr[4 * i + 2] = t.z; vr[4 * i + 3] = t.w;
    }
    const float* urow = u_to_e + (size_t)nodes[b] * D;
#pragma unroll
    for (int d = 0; d < D; ++d) {
        const float* w1 = att1_w + d * TWO_D;
        float a0 = att1_b[d], a1 = 0.f, a2 = 0.f, a3 = 0.f;
#pragma unroll
        for (int f = 0; f < D; f += 4) {
            a0 += vr[f + 0] * w1[f + 0];
            a1 += vr[f + 1] * w1[f + 1];
            a2 += vr[f + 2] * w1[f + 2];
            a3 += vr[f + 3] * w1[f + 3];
            a0 += urow[f + 0] * w1[D + f + 0];
            a1 += urow[f + 1] * w1[D + f + 1];
            a2 += urow[f + 2] * w1[D + f + 2];
            a3 += urow[f + 3] * w1[D + f + 3];
        }
        h1[d] = fmaxf((a0 + a1) + (a2 + a3), 0.f);
    }

    float logit = att3_b[0];
#pragma unroll 4
    for (int e = 0; e < D; ++e) {
        const float* w2r = att2_w + e * D;
        float a0 = 0.f, a1 = 0.f, a2 = 0.f, a3 = 0.f;
#pragma unroll
        for (int dd = 0; dd < D; dd += 4) {
            a0 += h1[dd + 0] * w2r[dd + 0];
            a1 += h1[dd + 1] * w2r[dd + 1];
            a2 += h1[dd + 2] * w2r[dd + 2];
            a3 += h1[dd + 3] * w2r[dd + 3];
        }
        float h2 = (a0 + a1) + (a2 + a3) + att2_b[e];
        logit += fmaxf(h2, 0.f) * att3_w[e];
    }

    float ml = active ? logit : -1e30f;
#pragma unroll
    for (int off = 32; off > 0; off >>= 1) ml = fmaxf(ml, __shfl_xor(ml, off));
    const float ex = active ? __expf(logit - ml) : 0.f;
    float smv = ex;
#pragma unroll
    for (int off = 32; off > 0; off >>= 1) smv += __shfl_xor(smv, off);
    const float att = ex / smv;

    float acc = 0.f;
    for (int kk = 0; kk < deg; ++kk) {
        const float a  = __shfl(att, kk);
        const int   vk = __shfl(v, kk);
        acc += a * v_to_e[(size_t)vk * D + lane];
    }
    out[(size_t)b * D + lane] = acc;
}

// ---------------------------------------------------------------------------
extern "C" void kernel_launch(void* const* d_in, const int* in_sizes, int n_in,
                              void* d_out, int out_size, void* d_ws, size_t ws_size,
                              hipStream_t stream)
{
    const int*   nodes   = (const int*)d_in[0];
    const int*   history = (const int*)d_in[1];
    const int*   degrees = (const int*)d_in[2];
    const float* u_to_e  = (const float*)d_in[3];
    const float* v_to_e  = (const float*)d_in[4];
    const float* att1_w  = (const float*)d_in[5];
    const float* att1_b  = (const float*)d_in[6];
    const float* att2_w  = (const float*)d_in[7];
    const float* att2_b  = (const float*)d_in[8];
    const float* att3_w  = (const float*)d_in[9];
    const float* att3_b  = (const float*)d_in[10];
    float*       out     = (float*)d_out;

    const int Bn = in_sizes[0];
    const int K  = in_sizes[1] / Bn;
    const int NV = in_sizes[4] / D;

    // ws: P16 (bf16 NV*D) | S (fp32 Bn*D) | W2F (8 KB) | V16 (bf16 NV*D)
    const size_t p16_bytes = (size_t)NV * D * sizeof(unsigned short);
    const size_t s_bytes   = (size_t)Bn * D * sizeof(float);
    const size_t w2f_bytes = (size_t)8 * 64 * 8 * sizeof(unsigned short);
    const size_t v16_bytes = (size_t)NV * D * sizeof(unsigned short);
    const size_t need = p16_bytes + s_bytes + w2f_bytes + v16_bytes;

    if (ws_size >= need) {
        char* p = (char*)d_ws;
        unsigned short* P16 = (unsigned short*)p;   p += p16_bytes;
        float*          S   = (float*)p;            p += s_bytes;
        unsigned short* W2F = (unsigned short*)p;   p += w2f_bytes;
        unsigned short* V16 = (unsigned short*)p;
        const int nPB = (NV + 63) / 64;
        const int nSB = (Bn + 63) / 64;
        proj_gemm<<<nPB + nSB + 1, 256, 0, stream>>>(
            v_to_e, u_to_e, nodes, att1_w, att1_b, att2_w,
            P16, S, W2F, V16, NV, Bn, nPB);
        agg_mfma<<<Bn, 256, 0, stream>>>(
            history, degrees, att2_b, att3_w,
            P16, S, W2F, V16, out, Bn, K);
    } else {
        const int agg_blocks = (Bn * 64 + 255) / 256;
        agg_fallback<<<agg_blocks, 256, 0, stream>>>(
            nodes, history, degrees, u_to_e, v_to_e,
            att1_w, att1_b, att2_w, att2_b, att3_w, att3_b,
            out, Bn, K);
    }
}

// Round 14
// 43.951 us; speedup vs baseline: 1.3133x; 1.1778x over previous
//
#include <hip/hip_runtime.h>
#include <cstdint>
#include <cstddef>

constexpr int D = 64;
constexpr int TWO_D = 128;

typedef __attribute__((ext_vector_type(8))) short bf16x8;
typedef __attribute__((ext_vector_type(4))) float f32x4;
typedef __attribute__((ext_vector_type(4))) unsigned short u16x4;

static __device__ __forceinline__ short f2bf(float x) {
    unsigned u = __builtin_bit_cast(unsigned, x);
    u += 0x7fffu + ((u >> 16) & 1u);          // round-to-nearest-even
    return (short)(u >> 16);
}
static __device__ __forceinline__ float bf2f(unsigned short h) {
    return __builtin_bit_cast(float, ((unsigned)h) << 16);
}
static __device__ __forceinline__ bf16x8 cvt8(const float* p) {
    const float4 a = *(const float4*)p;
    const float4 c = *(const float4*)(p + 4);
    bf16x8 f;
    f[0] = f2bf(a.x); f[1] = f2bf(a.y); f[2] = f2bf(a.z); f[3] = f2bf(a.w);
    f[4] = f2bf(c.x); f[5] = f2bf(c.y); f[6] = f2bf(c.z); f[7] = f2bf(c.w);
    return f;
}

// ---------------------------------------------------------------------------
// Kernel 1: S table only (tiny GEMM) + W1F/W2F fragment pack.
//   blocks [0, nSB):  S[b,:] = u_to_e[nodes[b],:] . att1_w[:,D:2D]^T + b1
//   block  nSB:       W1F = bf16 A-fragments of att1_w[:,0:D]  (neighbor half)
//                     W2F = bf16 A-fragments of att2_w
// ---------------------------------------------------------------------------
__global__ __launch_bounds__(256) void proj_s(
    const float* __restrict__ u_to_e, const int* __restrict__ nodes,
    const float* __restrict__ att1_w, const float* __restrict__ att1_b,
    const float* __restrict__ att2_w,
    float* __restrict__ S, unsigned short* __restrict__ W1F,
    unsigned short* __restrict__ W2F,
    int Bn, int nSB)
{
    const int tid = threadIdx.x;

    if ((int)blockIdx.x == nSB) {                    // pack block
        if (tid < 64) {
            const int plg = tid >> 4, plc = tid & 15;
#pragma unroll
            for (int tc = 0; tc < 4; ++tc)
#pragma unroll
                for (int ks = 0; ks < 2; ++ks) {
                    // W1 neighbor half: row stride 2D, cols [0,64)
                    const bf16x8 f1 = cvt8(
                        att1_w + (tc * 16 + plc) * TWO_D + ks * 32 + plg * 8);
                    *(bf16x8*)(W1F + ((size_t)(tc * 2 + ks) * 64 + tid) * 8) = f1;
                    // W2: row stride D
                    const bf16x8 f2 = cvt8(
                        att2_w + (tc * 16 + plc) * D + ks * 32 + plg * 8);
                    *(bf16x8*)(W2F + ((size_t)(tc * 2 + ks) * 64 + tid) * 8) = f2;
                }
        }
        return;
    }

    constexpr int ST = 68;
    __shared__ float xs[64 * ST];
    __shared__ float ws[64 * ST];

    const int base = (int)blockIdx.x * 64;

#pragma unroll
    for (int it = 0; it < 4; ++it) {
        const int flat = it * 256 + tid;
        const int dd = flat >> 4, f4 = flat & 15;
        const float4 w = *(const float4*)(att1_w + dd * TWO_D + D + f4 * 4);
        ws[(f4 * 4 + 0) * ST + dd] = w.x;
        ws[(f4 * 4 + 1) * ST + dd] = w.y;
        ws[(f4 * 4 + 2) * ST + dd] = w.z;
        ws[(f4 * 4 + 3) * ST + dd] = w.w;
    }
#pragma unroll
    for (int it = 0; it < 4; ++it) {
        const int flat = it * 256 + tid;
        const int r = flat >> 4, f4 = flat & 15;
        int gr = base + r;
        if (gr >= Bn) gr = Bn - 1;
        const int row = nodes[gr];
        const float4 x = *(const float4*)(u_to_e + (size_t)row * D + f4 * 4);
        xs[(f4 * 4 + 0) * ST + r] = x.x;
        xs[(f4 * 4 + 1) * ST + r] = x.y;
        xs[(f4 * 4 + 2) * ST + r] = x.z;
        xs[(f4 * 4 + 3) * ST + r] = x.w;
    }
    __syncthreads();

    const int d0 = (tid & 15) * 4;
    const int r0 = (tid >> 4) * 4;
    float acc[4][4];
#pragma unroll
    for (int i = 0; i < 4; ++i)
#pragma unroll
        for (int j = 0; j < 4; ++j) acc[i][j] = 0.f;

#pragma unroll 8
    for (int f = 0; f < D; ++f) {
        const float4 w = *(const float4*)&ws[f * ST + d0];
        const float4 x = *(const float4*)&xs[f * ST + r0];
        const float wv[4] = {w.x, w.y, w.z, w.w};
        const float xv[4] = {x.x, x.y, x.z, x.w};
#pragma unroll
        for (int ri = 0; ri < 4; ++ri)
#pragma unroll
            for (int di = 0; di < 4; ++di)
                acc[ri][di] += xv[ri] * wv[di];
    }

    float bv[4];
#pragma unroll
    for (int di = 0; di < 4; ++di) bv[di] = att1_b[d0 + di];
#pragma unroll
    for (int ri = 0; ri < 4; ++ri) {
        const int gr = base + r0 + ri;
        if (gr < Bn) {
            float4 o = {acc[ri][0] + bv[0], acc[ri][1] + bv[1],
                        acc[ri][2] + bv[2], acc[ri][3] + bv[3]};
            *(float4*)(S + (size_t)gr * D + d0) = o;
        }
    }
}

// ---------------------------------------------------------------------------
// Kernel 2 (fully fused): block = one b, wave wslot = k-tile [16w, 16w+16).
// h1 computed ON THE FLY from the gathered v rows (no P16 table):
//   H1T[d][k] = mfma(W1F, v_frag)  ->  +S, relu, bf16  ->  per-wave LDS tile
//   (stride-72 ushort rows; ds_write_b64 / ds_read_b128, ~conflict-free)
//   -> af fragments -> W2 mfma -> logits -> flash softmax -> value FMA.
// Value rows prefetched FIRST (R7 overlap); B-frag v loads hit L1 (same rows).
// ---------------------------------------------------------------------------
__global__ __launch_bounds__(256) void agg_fused(
    const int* __restrict__ history, const int* __restrict__ degrees,
    const float* __restrict__ v_to_e,
    const float* __restrict__ att2_b, const float* __restrict__ att3_w,
    const float* __restrict__ S,
    const unsigned short* __restrict__ W1F,
    const unsigned short* __restrict__ W2F,
    float* __restrict__ out, int Bn, int K)
{
    __shared__ unsigned short hldsb[4][16 * 72];   // 9.2 KB bf16 h1 tiles
    __shared__ float red[4][64];
    __shared__ float mxs[4];
    __shared__ float sms[4];

    const int b     = (int)blockIdx.x;
    const int wslot = threadIdx.x >> 6;
    const int l     = threadIdx.x & 63;
    const int lg    = l >> 4;
    const int lc    = l & 15;
    const int deg   = degrees[b];                 // uniform
    const bool live = (wslot * 16 < deg);         // wave-uniform
    const bool act  = (wslot * 16 + lc < deg);

    int kk = wslot * 16 + lc;
    if (kk > K - 1) kk = K - 1;
    const int vrow = history[(size_t)b * K + kk];   // row id for k_local = lc

    // ---- value prefetch FIRST: 4 wide fp32 loads (4 rows each, R10) ----
    float4 vr4[4];
    if (live) {
#pragma unroll
        for (int jj = 0; jj < 4; ++jj) {
            const int row = __shfl(vrow, jj * 4 + lg);
            vr4[jj] = *(const float4*)(v_to_e + (size_t)row * D + lc * 4);
        }
    }

    float m_w = -1e30f, ex = 0.f;
    float4 acc4 = {0.f, 0.f, 0.f, 0.f};
    if (live) {
        // ---- B-frag of v for the H1T MFMA (same rows as value path -> L1) --
        const float* vp = v_to_e + (size_t)vrow * D;
        const bf16x8 bv0 = cvt8(vp + lg * 8);          // feat 0..31 slice
        const bf16x8 bv1 = cvt8(vp + 32 + lg * 8);     // feat 32..63 slice

        // ---- per-tc: H1T chunk = W1n x v^T; +S, relu, bf16 -> LDS ----
        unsigned short* hrow = &hldsb[wslot][0];
#pragma unroll
        for (int tc = 0; tc < 4; ++tc) {
            f32x4 hacc = (f32x4)0.f;
            const bf16x8 w10 = *(const bf16x8*)(
                W1F + ((size_t)(tc * 2 + 0) * 64 + l) * 8);
            hacc = __builtin_amdgcn_mfma_f32_16x16x32_bf16(w10, bv0, hacc, 0, 0, 0);
            const bf16x8 w11 = *(const bf16x8*)(
                W1F + ((size_t)(tc * 2 + 1) * 64 + l) * 8);
            hacc = __builtin_amdgcn_mfma_f32_16x16x32_bf16(w11, bv1, hacc, 0, 0, 0);
            // lane holds H1T[d = tc*16 + lg*4 + r][neighbor lc]
            const float4 sv = *(const float4*)(S + (size_t)b * D + tc * 16 + lg * 4);
            u16x4 hb;
            hb[0] = (unsigned short)f2bf(fmaxf(hacc[0] + sv.x, 0.f));
            hb[1] = (unsigned short)f2bf(fmaxf(hacc[1] + sv.y, 0.f));
            hb[2] = (unsigned short)f2bf(fmaxf(hacc[2] + sv.z, 0.f));
            hb[3] = (unsigned short)f2bf(fmaxf(hacc[3] + sv.w, 0.f));
            // store at row = neighbor lc, col = d  (stride 72 ushorts)
            *(u16x4*)&hrow[lc * 72 + tc * 16 + lg * 4] = hb;
        }

        // ---- same-wave LDS read in af layout (R4-proven, no barrier) ----
        // af0[j] = h1[neighbor lc][d = lg*8 + j], af1: d = 32 + lg*8 + j
        const bf16x8 af0 = *(const bf16x8*)&hrow[lc * 72 + lg * 8];
        const bf16x8 af1 = *(const bf16x8*)&hrow[lc * 72 + 32 + lg * 8];

        // ---- per-tc W2 MFMA + fused epilogue (single live accumulator) ----
        float part = 0.f;
#pragma unroll
        for (int tc = 0; tc < 4; ++tc) {
            f32x4 acc = (f32x4)0.f;
            const bf16x8 w0 = *(const bf16x8*)(
                W2F + ((size_t)(tc * 2 + 0) * 64 + l) * 8);
            acc = __builtin_amdgcn_mfma_f32_16x16x32_bf16(w0, af0, acc, 0, 0, 0);
            const bf16x8 w1 = *(const bf16x8*)(
                W2F + ((size_t)(tc * 2 + 1) * 64 + l) * 8);
            acc = __builtin_amdgcn_mfma_f32_16x16x32_bf16(w1, af1, acc, 0, 0, 0);
            const float4 b2v = *(const float4*)(att2_b + tc * 16 + lg * 4);
            const float4 w3v = *(const float4*)(att3_w + tc * 16 + lg * 4);
            part += fmaxf(acc[0] + b2v.x, 0.f) * w3v.x;
            part += fmaxf(acc[1] + b2v.y, 0.f) * w3v.y;
            part += fmaxf(acc[2] + b2v.z, 0.f) * w3v.z;
            part += fmaxf(acc[3] + b2v.w, 0.f) * w3v.w;
        }
        part += __shfl_xor(part, 16);
        part += __shfl_xor(part, 32);
        const float logit = act ? part : -1e30f;

        // ---- per-wave softmax partials (flash style) ----
        m_w = logit;
#pragma unroll
        for (int off = 1; off < 16; off <<= 1)
            m_w = fmaxf(m_w, __shfl_xor(m_w, off));
        ex = act ? __expf(logit - m_w) : 0.f;
        float s_w = ex;
#pragma unroll
        for (int off = 1; off < 16; off <<= 1)
            s_w += __shfl_xor(s_w, off);
        if (l == 0) { mxs[wslot] = m_w; sms[wslot] = s_w; }

        // ---- value FMA with unnormalized weights (before barrier) ----
#pragma unroll
        for (int jj = 0; jj < 4; ++jj) {
            const float a = __shfl(ex, jj * 4 + lg);
            acc4.x += a * vr4[jj].x;
            acc4.y += a * vr4[jj].y;
            acc4.z += a * vr4[jj].z;
            acc4.w += a * vr4[jj].w;
        }
        acc4.x += __shfl_xor(acc4.x, 16); acc4.x += __shfl_xor(acc4.x, 32);
        acc4.y += __shfl_xor(acc4.y, 16); acc4.y += __shfl_xor(acc4.y, 32);
        acc4.z += __shfl_xor(acc4.z, 16); acc4.z += __shfl_xor(acc4.z, 32);
        acc4.w += __shfl_xor(acc4.w, 16); acc4.w += __shfl_xor(acc4.w, 32);
    } else {
        if (l == 0) { mxs[wslot] = -1e30f; sms[wslot] = 0.f; }
    }

    __syncthreads();
    const float m = fmaxf(fmaxf(mxs[0], mxs[1]), fmaxf(mxs[2], mxs[3]));
    const float tot = sms[0] * __expf(mxs[0] - m) + sms[1] * __expf(mxs[1] - m)
                    + sms[2] * __expf(mxs[2] - m) + sms[3] * __expf(mxs[3] - m);
    const float scale = live ? __expf(m_w - m) / tot : 0.f;

    const float comp = (lg == 0) ? acc4.x : (lg == 1) ? acc4.y
                     : (lg == 2) ? acc4.z : acc4.w;
    red[wslot][lc * 4 + lg] = comp * scale;
    __syncthreads();
    if (wslot == 0)
        out[(size_t)b * D + l] =
            (red[0][l] + red[1][l]) + (red[2][l] + red[3][l]);
}

// ---------------------------------------------------------------------------
// Fallback (no workspace): fused fp32 kernel, one wave per b.
// ---------------------------------------------------------------------------
__global__ __launch_bounds__(256) void agg_fallback(
    const int* __restrict__ nodes, const int* __restrict__ history,
    const int* __restrict__ degrees,
    const float* __restrict__ u_to_e, const float* __restrict__ v_to_e,
    const float* __restrict__ att1_w, const float* __restrict__ att1_b,
    const float* __restrict__ att2_w, const float* __restrict__ att2_b,
    const float* __restrict__ att3_w, const float* __restrict__ att3_b,
    float* __restrict__ out, int Bn, int K)
{
    const int b    = (int)((blockIdx.x * blockDim.x + threadIdx.x) >> 6);
    const int lane = threadIdx.x & 63;
    if (b >= Bn) return;

    const int  deg    = degrees[b];
    const bool active = (lane < deg);
    const int  v      = history[(size_t)b * K + ((lane < K) ? lane : 0)];

    float h1[D];
    float vr[D];
    const float4* v4 = (const float4*)(v_to_e + (size_t)v * D);
#pragma unroll
    for (int i = 0; i < D / 4; ++i) {
        float4 t = v4[i];
        vr[4 * i + 0] = t.x; vr[4 * i + 1] = t.y;
        vr[4 * i + 2] = t.z; vr[4 * i + 3] = t.w;
    }
    const float* urow = u_to_e + (size_t)nodes[b] * D;
#pragma unroll
    for (int d = 0; d < D; ++d) {
        const float* w1 = att1_w + d * TWO_D;
        float a0 = att1_b[d], a1 = 0.f, a2 = 0.f, a3 = 0.f;
#pragma unroll
        for (int f = 0; f < D; f += 4) {
            a0 += vr[f + 0] * w1[f + 0];
            a1 += vr[f + 1] * w1[f + 1];
            a2 += vr[f + 2] * w1[f + 2];
            a3 += vr[f + 3] * w1[f + 3];
            a0 += urow[f + 0] * w1[D + f + 0];
            a1 += urow[f + 1] * w1[D + f + 1];
            a2 += urow[f + 2] * w1[D + f + 2];
            a3 += urow[f + 3] * w1[D + f + 3];
        }
        h1[d] = fmaxf((a0 + a1) + (a2 + a3), 0.f);
    }

    float logit = att3_b[0];
#pragma unroll 4
    for (int e = 0; e < D; ++e) {
        const float* w2r = att2_w + e * D;
        float a0 = 0.f, a1 = 0.f, a2 = 0.f, a3 = 0.f;
#pragma unroll
        for (int dd = 0; dd < D; dd += 4) {
            a0 += h1[dd + 0] * w2r[dd + 0];
            a1 += h1[dd + 1] * w2r[dd + 1];
            a2 += h1[dd + 2] * w2r[dd + 2];
            a3 += h1[dd + 3] * w2r[dd + 3];
        }
        float h2 = (a0 + a1) + (a2 + a3) + att2_b[e];
        logit += fmaxf(h2, 0.f) * att3_w[e];
    }

    float ml = active ? logit : -1e30f;
#pragma unroll
    for (int off = 32; off > 0; off >>= 1) ml = fmaxf(ml, __shfl_xor(ml, off));
    const float ex = active ? __expf(logit - ml) : 0.f;
    float smv = ex;
#pragma unroll
    for (int off = 32; off > 0; off >>= 1) smv += __shfl_xor(smv, off);
    const float att = ex / smv;

    float acc = 0.f;
    for (int kk = 0; kk < deg; ++kk) {
        const float a  = __shfl(att, kk);
        const int   vk = __shfl(v, kk);
        acc += a * v_to_e[(size_t)vk * D + lane];
    }
    out[(size_t)b * D + lane] = acc;
}

// ---------------------------------------------------------------------------
extern "C" void kernel_launch(void* const* d_in, const int* in_sizes, int n_in,
                              void* d_out, int out_size, void* d_ws, size_t ws_size,
                              hipStream_t stream)
{
    const int*   nodes   = (const int*)d_in[0];
    const int*   history = (const int*)d_in[1];
    const int*   degrees = (const int*)d_in[2];
    const float* u_to_e  = (const float*)d_in[3];
    const float* v_to_e  = (const float*)d_in[4];
    const float* att1_w  = (const float*)d_in[5];
    const float* att1_b  = (const float*)d_in[6];
    const float* att2_w  = (const float*)d_in[7];
    const float* att2_b  = (const float*)d_in[8];
    const float* att3_w  = (const float*)d_in[9];
    const float* att3_b  = (const float*)d_in[10];
    float*       out     = (float*)d_out;

    const int Bn = in_sizes[0];
    const int K  = in_sizes[1] / Bn;

    // ws: S (fp32 Bn*D) | W1F (8 KB) | W2F (8 KB)
    const size_t s_bytes   = (size_t)Bn * D * sizeof(float);
    const size_t wf_bytes  = (size_t)8 * 64 * 8 * sizeof(unsigned short);
    const size_t need = s_bytes + 2 * wf_bytes;

    if (ws_size >= need) {
        char* p = (char*)d_ws;
        float*          S   = (float*)p;            p += s_bytes;
        unsigned short* W1F = (unsigned short*)p;   p += wf_bytes;
        unsigned short* W2F = (unsigned short*)p;
        const int nSB = (Bn + 63) / 64;
        proj_s<<<nSB + 1, 256, 0, stream>>>(
            u_to_e, nodes, att1_w, att1_b, att2_w, S, W1F, W2F, Bn, nSB);
        agg_fused<<<Bn, 256, 0, stream>>>(
            history, degrees, v_to_e, att2_b, att3_w,
            S, W1F, W2F, out, Bn, K);
    } else {
        const int agg_blocks = (Bn * 64 + 255) / 256;
        agg_fallback<<<agg_blocks, 256, 0, stream>>>(
            nodes, history, degrees, u_to_e, v_to_e,
            att1_w, att1_b, att2_w, att2_b, att3_w, att3_b,
            out, Bn, K);
    }
}